// Round 8
// baseline (251.877 us; speedup 1.0000x reference)
//
#include <hip/hip_runtime.h>

#define B_ 16
#define N_ 1024
#define F_ 16
#define E_ 12
#define H_ 4

// 16 blocks x 256 threads: block owns batch b ENTIRELY (x + y sides, 2048 tokens).
// Zero cross-block communication, zero workspace. Phases recompute projections from
// L2-resident inputs instead of carrying them in registers (avoids spill).

// shared-weight offsets
#define SW_WIN   0      // 192
#define SW_BIN   192    // 12
#define SW_WQKVS 204    // 432
#define SW_BQKVS 636    // 36
#define SW_WOS   672    // 144
#define SW_BOS   816    // 12
#define SW_WQKVC 828    // 432
#define SW_BQKVC 1260   // 36
#define SW_WOC   1296   // 144
#define SW_BOC   1440   // 12
#define SW_WOUT  1452   // 36
#define SW_BOUT  1488   // 3
#define SW_TOT   1491

// moment layout per head (39 used, stride 40):
// [0:3]=Sum k | [3:9]=Sum kk (00,11,22,01,02,12) | [9:12]=Sum v
// [12:21]=Sum k_i v_c | [21:39]=Sum kk_pair v_c

__device__ __forceinline__ void mom_compute(float k0, float k1, float k2,
                                            float v0, float v1, float v2, float* m) {
  m[0]=k0; m[1]=k1; m[2]=k2;
  float s00=k0*k0, s11=k1*k1, s22=k2*k2, s01=k0*k1, s02=k0*k2, s12=k1*k2;
  m[3]=s00; m[4]=s11; m[5]=s22; m[6]=s01; m[7]=s02; m[8]=s12;
  m[9]=v0; m[10]=v1; m[11]=v2;
  m[12]=k0*v0; m[13]=k0*v1; m[14]=k0*v2;
  m[15]=k1*v0; m[16]=k1*v1; m[17]=k1*v2;
  m[18]=k2*v0; m[19]=k2*v1; m[20]=k2*v2;
  m[21]=s00*v0; m[22]=s00*v1; m[23]=s00*v2;
  m[24]=s11*v0; m[25]=s11*v1; m[26]=s11*v2;
  m[27]=s22*v0; m[28]=s22*v1; m[29]=s22*v2;
  m[30]=s01*v0; m[31]=s01*v1; m[32]=s01*v2;
  m[33]=s02*v0; m[34]=s02*v1; m[35]=s02*v2;
  m[36]=s12*v0; m[37]=s12*v1; m[38]=s12*v2;
}

__device__ __forceinline__ void mom_accum(float k0, float k1, float k2,
                                          float v0, float v1, float v2, float* m) {
  m[0]+=k0; m[1]+=k1; m[2]+=k2;
  float s00=k0*k0, s11=k1*k1, s22=k2*k2, s01=k0*k1, s02=k0*k2, s12=k1*k2;
  m[3]+=s00; m[4]+=s11; m[5]+=s22; m[6]+=s01; m[7]+=s02; m[8]+=s12;
  m[9]+=v0; m[10]+=v1; m[11]+=v2;
  m[12]+=k0*v0; m[13]+=k0*v1; m[14]+=k0*v2;
  m[15]+=k1*v0; m[16]+=k1*v1; m[17]+=k1*v2;
  m[18]+=k2*v0; m[19]+=k2*v1; m[20]+=k2*v2;
  m[21]+=s00*v0; m[22]+=s00*v1; m[23]+=s00*v2;
  m[24]+=s11*v0; m[25]+=s11*v1; m[26]+=s11*v2;
  m[27]+=s22*v0; m[28]+=s22*v1; m[29]+=s22*v2;
  m[30]+=s01*v0; m[31]+=s01*v1; m[32]+=s01*v2;
  m[33]+=s02*v0; m[34]+=s02*v1; m[35]+=s02*v2;
  m[36]+=s12*v0; m[37]+=s12*v1; m[38]+=s12*v2;
}

// eval with pre-scaled moments (diag 2nd-order entries x0.5 applied at LDS stage)
__device__ __forceinline__ void attn_eval(const float* __restrict__ mu,
                                          float p0, float p1, float p2, float* out) {
  float pp0=p0*p0, pp1=p1*p1, pp2=p2*p2;
  float q01=p0*p1, q02=p0*p2, q12=p1*p2;
  float den = (float)N_;
  den = fmaf(p0, mu[0], den); den = fmaf(p1, mu[1], den); den = fmaf(p2, mu[2], den);
  den = fmaf(pp0, mu[3], den); den = fmaf(pp1, mu[4], den); den = fmaf(pp2, mu[5], den);
  den = fmaf(q01, mu[6], den); den = fmaf(q02, mu[7], den); den = fmaf(q12, mu[8], den);
  float inv = 1.0f / den;
#pragma unroll
  for (int c = 0; c < 3; c++) {
    float num = mu[9+c];
    num = fmaf(p0, mu[12+c], num); num = fmaf(p1, mu[15+c], num); num = fmaf(p2, mu[18+c], num);
    num = fmaf(pp0, mu[21+c], num); num = fmaf(pp1, mu[24+c], num); num = fmaf(pp2, mu[27+c], num);
    num = fmaf(q01, mu[30+c], num); num = fmaf(q02, mu[33+c], num); num = fmaf(q12, mu[36+c], num);
    out[c] = num * inv;
  }
}

__device__ __forceinline__ float mom_scale(int j) {
  return ((j >= 3 && j < 6) || (j >= 21 && j < 30)) ? 0.5f : 1.0f;
}

__global__ __launch_bounds__(256, 1)
void k_all(const float* __restrict__ xo, const float* __restrict__ yo,
           const float* __restrict__ W_in, const float* __restrict__ b_in,
           const float* __restrict__ Wqkv_s, const float* __restrict__ bqkv_s,
           const float* __restrict__ Wo_s, const float* __restrict__ bo_s,
           const float* __restrict__ Wqkv_c, const float* __restrict__ bqkv_c,
           const float* __restrict__ Wo_c, const float* __restrict__ bo_c,
           const float* __restrict__ W_out, const float* __restrict__ b_out,
           float* __restrict__ out) {
  __shared__ float sw[SW_TOT];
  __shared__ float red[64 * 180];   // [quad64][176 used, stride 180]
  __shared__ float rawRx[176], rawRy[176];
  __shared__ float smuX[160], smuY[160], smuC[160];
  __shared__ float dqX[12], dqY[12];
  __shared__ float sredK[4][15];
  __shared__ float sXf[12];

  int tid = threadIdx.x;
  int b = blockIdx.x;
  int qd = tid >> 2;
  bool rep = (tid & 3) == 0;
  const float SC = 0.57735026918962584f;   // 1/sqrt(3)
  const float invN = 1.0f / N_;
  const float Nf = (float)N_;

  // persistent per-thread state (only these survive across phases)
  float xr[4][3];                   // x3 raw (A) -> centered (C)
  float qc[4][12];                  // cross-q (B-x -> C)

  // ---- weights -> LDS ----
  for (int i = tid; i < SW_TOT; i += 256) {
    float v;
    if (i < 192)       v = W_in[i];
    else if (i < 204)  v = b_in[i - 192];
    else if (i < 636)  v = Wqkv_s[i - 204];
    else if (i < 672)  v = bqkv_s[i - 636];
    else if (i < 816)  v = Wo_s[i - 672];
    else if (i < 828)  v = bo_s[i - 816];
    else if (i < 1260) v = Wqkv_c[i - 828];
    else if (i < 1296) v = bqkv_c[i - 1260];
    else if (i < 1440) v = Wo_c[i - 1296];
    else if (i < 1452) v = bo_c[i - 1440];
    else if (i < 1488) v = W_out[i - 1452];
    else               v = b_out[i - 1488];
    sw[i] = v;
  }
  __syncthreads();

  // ================= Phase A: raw k/v moments + sums, x then y =================
#pragma unroll
  for (int sd = 0; sd < 2; sd++) {
    const float* src = sd ? yo : xo;
    float* raw = sd ? rawRy : rawRx;
#pragma unroll
    for (int p = 0; p < 2; p++) {
      float av[16], bv[16];
      {
        const float4* p0 = (const float4*)(src + ((size_t)b * N_ + p*512 + tid) * F_);
        const float4* p1 = (const float4*)(src + ((size_t)b * N_ + p*512 + 256 + tid) * F_);
#pragma unroll
        for (int q = 0; q < 4; q++) {
          float4 v0 = p0[q], v1 = p1[q];
          av[4*q+0]=v0.x; av[4*q+1]=v0.y; av[4*q+2]=v0.z; av[4*q+3]=v0.w;
          bv[4*q+0]=v1.x; bv[4*q+1]=v1.y; bv[4*q+2]=v1.z; bv[4*q+3]=v1.w;
        }
      }
      if (sd == 0) {
        xr[p*2][0]=av[0]; xr[p*2][1]=av[1]; xr[p*2][2]=av[2];
        xr[p*2+1][0]=bv[0]; xr[p*2+1][1]=bv[1]; xr[p*2+1][2]=bv[2];
      }
      float xiA[E_], xiB[E_];
#pragma unroll
      for (int e = 0; e < E_; e++) {
        float sa = sw[SW_BIN + e], sb = sa;
#pragma unroll
        for (int f = 0; f < F_; f++) {
          sa = fmaf(av[f], sw[SW_WIN + e*F_ + f], sa);
          sb = fmaf(bv[f], sw[SW_WIN + e*F_ + f], sb);
        }
        xiA[e] = sa; xiB[e] = sb;
      }
#pragma unroll
      for (int h = 0; h < H_; h++) {
        float ka[6], kb[6];          // k0..2, v0..2 per token
#pragma unroll
        for (int d = 0; d < 6; d++) {
          int o = 12 + (d/3)*12 + h*3 + (d%3);
          float sa = sw[SW_BQKVS + o], sb = sa;
#pragma unroll
          for (int e = 0; e < E_; e++) {
            sa = fmaf(xiA[e], sw[SW_WQKVS + o*E_ + e], sa);
            sb = fmaf(xiB[e], sw[SW_WQKVS + o*E_ + e], sb);
          }
          ka[d] = sa; kb[d] = sb;
        }
        float m[40];
        mom_compute(ka[0], ka[1], ka[2], ka[3], ka[4], ka[5], m);
        mom_accum (kb[0], kb[1], kb[2], kb[3], kb[4], kb[5], m);
        m[39] = 0.f;
#pragma unroll
        for (int j = 0; j < 39; j++) {
          m[j] += __shfl_xor(m[j], 1);
          m[j] += __shfl_xor(m[j], 2);
        }
        if (rep) {
          if (p == 0) {
#pragma unroll
            for (int j4 = 0; j4 < 10; j4++)
              *(float4*)&red[qd*180 + h*40 + j4*4] =
                make_float4(m[j4*4], m[j4*4+1], m[j4*4+2], m[j4*4+3]);
          } else {
#pragma unroll
            for (int j = 0; j < 40; j++) red[qd*180 + h*40 + j] += m[j];
          }
        }
      }
      {
        float s[F_];
#pragma unroll
        for (int f = 0; f < F_; f++) {
          float v = av[f] + bv[f];
          v += __shfl_xor(v, 1);
          v += __shfl_xor(v, 2);
          s[f] = v;
        }
        if (rep) {
          if (p == 0) {
#pragma unroll
            for (int j4 = 0; j4 < 4; j4++)
              *(float4*)&red[qd*180 + 160 + j4*4] =
                make_float4(s[j4*4], s[j4*4+1], s[j4*4+2], s[j4*4+3]);
          } else {
#pragma unroll
            for (int f = 0; f < F_; f++) red[qd*180 + 160 + f] += s[f];
          }
        }
      }
    }
    __syncthreads();
    for (int col = tid; col < 176; col += 256) {
      float a = 0.f;
      for (int q = 0; q < 64; q++) a += red[q*180 + col];
      raw[col] = a;
    }
    __syncthreads();
  }

  // ---- shifted-moment corrections: tid 0..7 = (side, head) ----
  if (tid < 8) {
    int side = tid >> 2, h = tid & 3;
    const float* R0 = side ? rawRy : rawRx;
    float* SM = side ? smuY : smuX;
    float* DQ = side ? dqY : dqX;
    float del[E_];
#pragma unroll
    for (int e = 0; e < E_; e++) {
      float s = 0.f;
#pragma unroll
      for (int f = 0; f < F_; f++) s = fmaf(R0[160+f], sw[SW_WIN + e*F_ + f], s);
      del[e] = s * invN;
    }
    float A[3], G[3];
#pragma unroll
    for (int d = 0; d < 3; d++) {
      float sq=0.f, sk=0.f, sv=0.f;
#pragma unroll
      for (int e = 0; e < E_; e++) {
        sq = fmaf(del[e], sw[SW_WQKVS + (h*3+d)*E_ + e], sq);
        sk = fmaf(del[e], sw[SW_WQKVS + (12 + h*3+d)*E_ + e], sk);
        sv = fmaf(del[e], sw[SW_WQKVS + (24 + h*3+d)*E_ + e], sv);
      }
      DQ[h*3+d] = sq; A[d] = sk; G[d] = sv;
    }
    const float* R = &R0[h*40];
    float S[39];
#pragma unroll
    for (int i = 0; i < 3; i++) S[i] = R[i] - Nf*A[i];
    const int PI[6] = {0,1,2,0,0,1}, PJ[6] = {0,1,2,1,2,2};
#pragma unroll
    for (int p = 0; p < 6; p++) {
      int i = PI[p], j = PJ[p];
      S[3+p] = R[3+p] - A[i]*R[j] - A[j]*R[i] + Nf*A[i]*A[j];
    }
#pragma unroll
    for (int cc = 0; cc < 3; cc++) S[9+cc] = R[9+cc] - Nf*G[cc];
#pragma unroll
    for (int i = 0; i < 3; i++)
#pragma unroll
      for (int cc = 0; cc < 3; cc++)
        S[12+i*3+cc] = R[12+i*3+cc] - A[i]*R[9+cc] - G[cc]*R[i] + Nf*A[i]*G[cc];
#pragma unroll
    for (int p = 0; p < 6; p++) {
      int i = PI[p], j = PJ[p];
#pragma unroll
      for (int cc = 0; cc < 3; cc++) {
        S[21+p*3+cc] = R[21+p*3+cc]
                     - A[i]*R[12+j*3+cc] - A[j]*R[12+i*3+cc]
                     - G[cc]*R[3+p]
                     + A[i]*A[j]*R[9+cc]
                     + A[i]*G[cc]*R[j] + A[j]*G[cc]*R[i]
                     - Nf*A[i]*A[j]*G[cc];
      }
    }
#pragma unroll
    for (int j = 0; j < 39; j++) SM[h*40+j] = S[j] * mom_scale(j);
    SM[h*40+39] = 0.f;
  }
  __syncthreads();

  // ================= Phase B-x: reload, recompute q, self-attn -> cross-q =================
#pragma unroll
  for (int p = 0; p < 2; p++) {
    float av[16], bv[16];
    {
      const float4* p0 = (const float4*)(xo + ((size_t)b * N_ + p*512 + tid) * F_);
      const float4* p1 = (const float4*)(xo + ((size_t)b * N_ + p*512 + 256 + tid) * F_);
#pragma unroll
      for (int q = 0; q < 4; q++) {
        float4 v0 = p0[q], v1 = p1[q];
        av[4*q+0]=v0.x; av[4*q+1]=v0.y; av[4*q+2]=v0.z; av[4*q+3]=v0.w;
        bv[4*q+0]=v1.x; bv[4*q+1]=v1.y; bv[4*q+2]=v1.z; bv[4*q+3]=v1.w;
      }
    }
    float xiA[E_], xiB[E_];
#pragma unroll
    for (int e = 0; e < E_; e++) {
      float sa = sw[SW_BIN + e], sb = sa;
#pragma unroll
      for (int f = 0; f < F_; f++) {
        sa = fmaf(av[f], sw[SW_WIN + e*F_ + f], sa);
        sb = fmaf(bv[f], sw[SW_WIN + e*F_ + f], sb);
      }
      xiA[e] = sa; xiB[e] = sb;
    }
    float attnA[E_], attnB[E_];
#pragma unroll
    for (int h = 0; h < H_; h++) {
      float qa[3], qb[3];
#pragma unroll
      for (int d = 0; d < 3; d++) {
        int o = h*3 + d;
        float sa = sw[SW_BQKVS + o], sb = sa;
#pragma unroll
        for (int e = 0; e < E_; e++) {
          sa = fmaf(xiA[e], sw[SW_WQKVS + o*E_ + e], sa);
          sb = fmaf(xiB[e], sw[SW_WQKVS + o*E_ + e], sb);
        }
        qa[d] = sa; qb[d] = sb;
      }
      attn_eval(&smuX[h*40], (qa[0]-dqX[h*3+0])*SC, (qa[1]-dqX[h*3+1])*SC,
                (qa[2]-dqX[h*3+2])*SC, &attnA[h*3]);
      attn_eval(&smuX[h*40], (qb[0]-dqX[h*3+0])*SC, (qb[1]-dqX[h*3+1])*SC,
                (qb[2]-dqX[h*3+2])*SC, &attnB[h*3]);
    }
    float i2a[E_], i2b[E_];
#pragma unroll
    for (int e = 0; e < E_; e++) {
      float sa = sw[SW_BOS + e], sb = sa;
#pragma unroll
      for (int j = 0; j < E_; j++) {
        sa = fmaf(attnA[j], sw[SW_WOS + e*E_ + j], sa);
        sb = fmaf(attnB[j], sw[SW_WOS + e*E_ + j], sb);
      }
      i2a[e] = sa; i2b[e] = sb;
    }
#pragma unroll
    for (int o = 0; o < 12; o++) {
      float sa = sw[SW_BQKVC + o], sb = sa;
#pragma unroll
      for (int e = 0; e < E_; e++) {
        sa = fmaf(i2a[e], sw[SW_WQKVC + o*E_ + e], sa);
        sb = fmaf(i2b[e], sw[SW_WQKVC + o*E_ + e], sb);
      }
      qc[p*2][o] = sa; qc[p*2+1][o] = sb;
    }
  }

  // ================= Phase B-y: reload, recompute, self-attn -> cross moments =================
#pragma unroll
  for (int p = 0; p < 2; p++) {
    float av[16], bv[16];
    {
      const float4* p0 = (const float4*)(yo + ((size_t)b * N_ + p*512 + tid) * F_);
      const float4* p1 = (const float4*)(yo + ((size_t)b * N_ + p*512 + 256 + tid) * F_);
#pragma unroll
      for (int q = 0; q < 4; q++) {
        float4 v0 = p0[q], v1 = p1[q];
        av[4*q+0]=v0.x; av[4*q+1]=v0.y; av[4*q+2]=v0.z; av[4*q+3]=v0.w;
        bv[4*q+0]=v1.x; bv[4*q+1]=v1.y; bv[4*q+2]=v1.z; bv[4*q+3]=v1.w;
      }
    }
    float xiA[E_], xiB[E_];
#pragma unroll
    for (int e = 0; e < E_; e++) {
      float sa = sw[SW_BIN + e], sb = sa;
#pragma unroll
      for (int f = 0; f < F_; f++) {
        sa = fmaf(av[f], sw[SW_WIN + e*F_ + f], sa);
        sb = fmaf(bv[f], sw[SW_WIN + e*F_ + f], sb);
      }
      xiA[e] = sa; xiB[e] = sb;
    }
    float attnA[E_], attnB[E_];
#pragma unroll
    for (int h = 0; h < H_; h++) {
      float qa[3], qb[3];
#pragma unroll
      for (int d = 0; d < 3; d++) {
        int o = h*3 + d;
        float sa = sw[SW_BQKVS + o], sb = sa;
#pragma unroll
        for (int e = 0; e < E_; e++) {
          sa = fmaf(xiA[e], sw[SW_WQKVS + o*E_ + e], sa);
          sb = fmaf(xiB[e], sw[SW_WQKVS + o*E_ + e], sb);
        }
        qa[d] = sa; qb[d] = sb;
      }
      attn_eval(&smuY[h*40], (qa[0]-dqY[h*3+0])*SC, (qa[1]-dqY[h*3+1])*SC,
                (qa[2]-dqY[h*3+2])*SC, &attnA[h*3]);
      attn_eval(&smuY[h*40], (qb[0]-dqY[h*3+0])*SC, (qb[1]-dqY[h*3+1])*SC,
                (qb[2]-dqY[h*3+2])*SC, &attnB[h*3]);
    }
    float i2a[E_], i2b[E_];
#pragma unroll
    for (int e = 0; e < E_; e++) {
      float sa = sw[SW_BOS + e], sb = sa;
#pragma unroll
      for (int j = 0; j < E_; j++) {
        sa = fmaf(attnA[j], sw[SW_WOS + e*E_ + j], sa);
        sb = fmaf(attnB[j], sw[SW_WOS + e*E_ + j], sb);
      }
      i2a[e] = sa; i2b[e] = sb;
    }
#pragma unroll
    for (int h = 0; h < H_; h++) {
      float ka[6], kb[6];
#pragma unroll
      for (int d = 0; d < 6; d++) {
        int o = 12 + (d/3)*12 + h*3 + (d%3);
        float sa = sw[SW_BQKVC + o], sb = sa;
#pragma unroll
        for (int e = 0; e < E_; e++) {
          sa = fmaf(i2a[e], sw[SW_WQKVC + o*E_ + e], sa);
          sb = fmaf(i2b[e], sw[SW_WQKVC + o*E_ + e], sb);
        }
        ka[d] = sa; kb[d] = sb;
      }
      float m[40];
      mom_compute(ka[0], ka[1], ka[2], ka[3], ka[4], ka[5], m);
      mom_accum (kb[0], kb[1], kb[2], kb[3], kb[4], kb[5], m);
      m[39] = 0.f;
#pragma unroll
      for (int j = 0; j < 39; j++) {
        m[j] += __shfl_xor(m[j], 1);
        m[j] += __shfl_xor(m[j], 2);
      }
      if (rep) {
        if (p == 0) {
#pragma unroll
          for (int j4 = 0; j4 < 10; j4++)
            *(float4*)&red[qd*180 + h*40 + j4*4] =
              make_float4(m[j4*4], m[j4*4+1], m[j4*4+2], m[j4*4+3]);
        } else {
#pragma unroll
          for (int j = 0; j < 40; j++) red[qd*180 + h*40 + j] += m[j];
        }
      }
    }
  }
  __syncthreads();
  for (int col = tid; col < 160; col += 256) {
    float a = 0.f;
    for (int q = 0; q < 64; q++) a += red[q*180 + col];
    int j = col - (col/40)*40;
    smuC[col] = a * mom_scale(j);
  }
  __syncthreads();

  // ================= Phase C: cross-attn + Kabsch stats =================
  {
    float st[15];
#pragma unroll
    for (int i = 0; i < 15; i++) st[i] = 0.f;
#pragma unroll
    for (int tk = 0; tk < 4; tk++) {
      float attn[E_], c12[E_], co[3];
#pragma unroll
      for (int h = 0; h < H_; h++)
        attn_eval(&smuC[h*40], qc[tk][h*3+0]*SC, qc[tk][h*3+1]*SC, qc[tk][h*3+2]*SC, &attn[h*3]);
#pragma unroll
      for (int e = 0; e < E_; e++) {
        float s = sw[SW_BOC + e];
#pragma unroll
        for (int j = 0; j < E_; j++) s = fmaf(attn[j], sw[SW_WOC + e*E_ + j], s);
        c12[e] = s;
      }
#pragma unroll
      for (int k = 0; k < 3; k++) {
        float s = sw[SW_BOUT + k];
#pragma unroll
        for (int e = 0; e < E_; e++) s = fmaf(c12[e], sw[SW_WOUT + k*E_ + e], s);
        co[k] = s;
      }
      xr[tk][0] -= rawRx[160]*invN; xr[tk][1] -= rawRx[161]*invN; xr[tk][2] -= rawRx[162]*invN;
      float A0 = co[0]+xr[tk][0], A1 = co[1]+xr[tk][1], A2 = co[2]+xr[tk][2];
      st[0]+=co[0]; st[1]+=co[1]; st[2]+=co[2];
      st[3]+=xr[tk][0]; st[4]+=xr[tk][1]; st[5]+=xr[tk][2];
      st[6]=fmaf(xr[tk][0],A0,st[6]);  st[7]=fmaf(xr[tk][0],A1,st[7]);  st[8]=fmaf(xr[tk][0],A2,st[8]);
      st[9]=fmaf(xr[tk][1],A0,st[9]);  st[10]=fmaf(xr[tk][1],A1,st[10]); st[11]=fmaf(xr[tk][1],A2,st[11]);
      st[12]=fmaf(xr[tk][2],A0,st[12]); st[13]=fmaf(xr[tk][2],A1,st[13]); st[14]=fmaf(xr[tk][2],A2,st[14]);
    }
#pragma unroll
    for (int i = 0; i < 15; i++) {
      st[i] += __shfl_down(st[i], 32); st[i] += __shfl_down(st[i], 16);
      st[i] += __shfl_down(st[i], 8);  st[i] += __shfl_down(st[i], 4);
      st[i] += __shfl_down(st[i], 2);  st[i] += __shfl_down(st[i], 1);
    }
    if ((tid & 63) == 0) {
      int wv = tid >> 6;
#pragma unroll
      for (int i = 0; i < 15; i++) sredK[wv][i] = st[i];
    }
  }
  __syncthreads();

  // ================= Phase D: polar (wave 0) + transform =================
  if (tid < 64) {
    float s[15];
#pragma unroll
    for (int i = 0; i < 15; i++) s[i] = sredK[0][i] + sredK[1][i] + sredK[2][i] + sredK[3][i];
    float cB[3] = { s[3]*invN, s[4]*invN, s[5]*invN };
    float cA[3] = { (s[0]+s[3])*invN, (s[1]+s[4])*invN, (s[2]+s[5])*invN };
    float X[9];
#pragma unroll
    for (int i = 0; i < 3; i++)
#pragma unroll
      for (int j = 0; j < 3; j++)
        X[i*3+j] = s[6 + i*3 + j] - Nf * cB[i] * cA[j];
    float fn = 0.f;
#pragma unroll
    for (int i = 0; i < 9; i++) fn += X[i]*X[i];
    float scl = rsqrtf(fn);
#pragma unroll
    for (int i = 0; i < 9; i++) X[i] *= scl;
    for (int it = 0; it < 24; it++) {
      float c00 =  X[4]*X[8]-X[5]*X[7];
      float c01 = -(X[3]*X[8]-X[5]*X[6]);
      float c02 =  X[3]*X[7]-X[4]*X[6];
      float c10 = -(X[1]*X[8]-X[2]*X[7]);
      float c11 =  X[0]*X[8]-X[2]*X[6];
      float c12_= -(X[0]*X[7]-X[1]*X[6]);
      float c20 =  X[1]*X[5]-X[2]*X[4];
      float c21 = -(X[0]*X[5]-X[2]*X[3]);
      float c22 =  X[0]*X[4]-X[1]*X[3];
      float det = X[0]*c00 + X[1]*c01 + X[2]*c02;
      float id = 0.5f / det;
      X[0]=0.5f*X[0]+c00*id; X[1]=0.5f*X[1]+c01*id; X[2]=0.5f*X[2]+c02*id;
      X[3]=0.5f*X[3]+c10*id; X[4]=0.5f*X[4]+c11*id; X[5]=0.5f*X[5]+c12_*id;
      X[6]=0.5f*X[6]+c20*id; X[7]=0.5f*X[7]+c21*id; X[8]=0.5f*X[8]+c22*id;
    }
    if (tid == 0) {
#pragma unroll
      for (int i = 0; i < 9; i++) sXf[i] = X[i];
#pragma unroll
      for (int k = 0; k < 3; k++)
        sXf[9+k] = cA[k] - (cB[0]*X[k] + cB[1]*X[3+k] + cB[2]*X[6+k]) + rawRy[160+k]*invN;
    }
  }
  __syncthreads();
  {
    float X0=sXf[0], X1=sXf[1], X2=sXf[2], X3=sXf[3], X4=sXf[4], X5=sXf[5],
          X6=sXf[6], X7=sXf[7], X8=sXf[8], t0=sXf[9], t1=sXf[10], t2=sXf[11];
#pragma unroll
    for (int tk = 0; tk < 4; tk++) {
      size_t t = (size_t)b * N_ + (tk>>1)*512 + (tk&1)*256 + tid;
      out[t*3+0] = fmaf(xr[tk][0], X0, fmaf(xr[tk][1], X3, fmaf(xr[tk][2], X6, t0)));
      out[t*3+1] = fmaf(xr[tk][0], X1, fmaf(xr[tk][1], X4, fmaf(xr[tk][2], X7, t1)));
      out[t*3+2] = fmaf(xr[tk][0], X2, fmaf(xr[tk][1], X5, fmaf(xr[tk][2], X8, t2)));
    }
  }
}

extern "C" void kernel_launch(void* const* d_in, const int* in_sizes, int n_in,
                              void* d_out, int out_size, void* d_ws, size_t ws_size,
                              hipStream_t stream) {
  const float* x_orig = (const float*)d_in[0];
  const float* y_orig = (const float*)d_in[1];
  const float* W_in   = (const float*)d_in[2];
  const float* b_in   = (const float*)d_in[3];
  const float* Wqkv_s = (const float*)d_in[4];
  const float* bqkv_s = (const float*)d_in[5];
  const float* Wo_s   = (const float*)d_in[6];
  const float* bo_s   = (const float*)d_in[7];
  const float* Wqkv_c = (const float*)d_in[8];
  const float* bqkv_c = (const float*)d_in[9];
  const float* Wo_c   = (const float*)d_in[10];
  const float* bo_c   = (const float*)d_in[11];
  const float* W_out  = (const float*)d_in[12];
  const float* b_out  = (const float*)d_in[13];

  k_all<<<B_, 256, 0, stream>>>(x_orig, y_orig, W_in, b_in, Wqkv_s, bqkv_s,
                                Wo_s, bo_s, Wqkv_c, bqkv_c, Wo_c, bo_c,
                                W_out, b_out, (float*)d_out);
}

// Round 9
// 135.637 us; speedup vs baseline: 1.8570x; 1.8570x over previous
//
#include <hip/hip_runtime.h>

#define B_ 16
#define N_ 1024
#define F_ 16
#define E_ 12
#define H_ 4

// 32 blocks x 256 threads: block (side,b) owns 1024 tokens of that side/batch.
// Per-token intermediates staged in LDS (xibuf), processed one token at a time
// (4 per thread) -> per-thread live set ~100 floats, no spill.
// Single cross-block hop: y-block publishes cross moments + y-mean -> x-block.
// ws: psC[16][160] | ymean[16][3] | flags[16] u64
#define OFF_PC 0
#define OFF_YM 2560
#define OFF_FLAG 2608   // float offset; byte 10432, 8-aligned
#define TAG_C 0x51A7E0C5ull

// shared-weight offsets
#define SW_WIN   0      // 192
#define SW_BIN   192    // 12
#define SW_WQKVS 204    // 432
#define SW_BQKVS 636    // 36
#define SW_WOS   672    // 144
#define SW_BOS   816    // 12
#define SW_WQKVC 828    // 432
#define SW_BQKVC 1260   // 36
#define SW_WOC   1296   // 144
#define SW_BOC   1440   // 12
#define SW_WOUT  1452   // 36
#define SW_BOUT  1488   // 3
#define SW_TOT   1491

// moment layout per head (39 used, stride 40):
// [0:3]=Sum k | [3:9]=Sum kk (00,11,22,01,02,12) | [9:12]=Sum v
// [12:21]=Sum k_i v_c | [21:39]=Sum kk_pair v_c

__device__ __forceinline__ void data_store(float* p, float v) {
  __hip_atomic_store((unsigned*)p, __float_as_uint(v),
                     __ATOMIC_RELAXED, __HIP_MEMORY_SCOPE_AGENT);
}
__device__ __forceinline__ float data_load(const float* p) {
  unsigned u = __hip_atomic_load((const unsigned*)p,
                                 __ATOMIC_RELAXED, __HIP_MEMORY_SCOPE_AGENT);
  return __uint_as_float(u);
}
__device__ __forceinline__ void flag_set(unsigned long long* f, unsigned long long tag) {
  __hip_atomic_store(f, tag, __ATOMIC_RELAXED, __HIP_MEMORY_SCOPE_AGENT);
}
__device__ __forceinline__ void flag_wait(unsigned long long* f, unsigned long long tag) {
  while (__hip_atomic_load(f, __ATOMIC_RELAXED, __HIP_MEMORY_SCOPE_AGENT) != tag)
    __builtin_amdgcn_s_sleep(2);
  asm volatile("" ::: "memory");
}

__device__ __forceinline__ void mom_accum(float k0, float k1, float k2,
                                          float v0, float v1, float v2, float* m) {
  m[0]+=k0; m[1]+=k1; m[2]+=k2;
  float s00=k0*k0, s11=k1*k1, s22=k2*k2, s01=k0*k1, s02=k0*k2, s12=k1*k2;
  m[3]+=s00; m[4]+=s11; m[5]+=s22; m[6]+=s01; m[7]+=s02; m[8]+=s12;
  m[9]+=v0; m[10]+=v1; m[11]+=v2;
  m[12]+=k0*v0; m[13]+=k0*v1; m[14]+=k0*v2;
  m[15]+=k1*v0; m[16]+=k1*v1; m[17]+=k1*v2;
  m[18]+=k2*v0; m[19]+=k2*v1; m[20]+=k2*v2;
  m[21]+=s00*v0; m[22]+=s00*v1; m[23]+=s00*v2;
  m[24]+=s11*v0; m[25]+=s11*v1; m[26]+=s11*v2;
  m[27]+=s22*v0; m[28]+=s22*v1; m[29]+=s22*v2;
  m[30]+=s01*v0; m[31]+=s01*v1; m[32]+=s01*v2;
  m[33]+=s02*v0; m[34]+=s02*v1; m[35]+=s02*v2;
  m[36]+=s12*v0; m[37]+=s12*v1; m[38]+=s12*v2;
}

// eval with pre-scaled moments (diag 2nd-order entries x0.5 applied at LDS stage)
__device__ __forceinline__ void attn_eval(const float* __restrict__ mu,
                                          float p0, float p1, float p2, float* out) {
  float pp0=p0*p0, pp1=p1*p1, pp2=p2*p2;
  float q01=p0*p1, q02=p0*p2, q12=p1*p2;
  float den = (float)N_;
  den = fmaf(p0, mu[0], den); den = fmaf(p1, mu[1], den); den = fmaf(p2, mu[2], den);
  den = fmaf(pp0, mu[3], den); den = fmaf(pp1, mu[4], den); den = fmaf(pp2, mu[5], den);
  den = fmaf(q01, mu[6], den); den = fmaf(q02, mu[7], den); den = fmaf(q12, mu[8], den);
  float inv = 1.0f / den;
#pragma unroll
  for (int c = 0; c < 3; c++) {
    float num = mu[9+c];
    num = fmaf(p0, mu[12+c], num); num = fmaf(p1, mu[15+c], num); num = fmaf(p2, mu[18+c], num);
    num = fmaf(pp0, mu[21+c], num); num = fmaf(pp1, mu[24+c], num); num = fmaf(pp2, mu[27+c], num);
    num = fmaf(q01, mu[30+c], num); num = fmaf(q02, mu[33+c], num); num = fmaf(q12, mu[36+c], num);
    out[c] = num * inv;
  }
}

__device__ __forceinline__ float mom_scale(int j) {
  return ((j >= 3 && j < 6) || (j >= 21 && j < 30)) ? 0.5f : 1.0f;
}

__global__ __launch_bounds__(256, 1)
void k_all(const float* __restrict__ xo, const float* __restrict__ yo,
           const float* __restrict__ W_in, const float* __restrict__ b_in,
           const float* __restrict__ Wqkv_s, const float* __restrict__ bqkv_s,
           const float* __restrict__ Wo_s, const float* __restrict__ bo_s,
           const float* __restrict__ Wqkv_c, const float* __restrict__ bqkv_c,
           const float* __restrict__ Wo_c, const float* __restrict__ bo_c,
           const float* __restrict__ W_out, const float* __restrict__ b_out,
           float* __restrict__ ws, float* __restrict__ out) {
  __shared__ float sw[SW_TOT];
  __shared__ float xibuf[1024 * 12];  // 48 KB: xi (A) -> qc (x) / i2 (y)
  __shared__ float x3buf[1024 * 3];   // 12 KB: raw x[:, :3] (x blocks)
  __shared__ float red[16 * 184];     // 11.8 KB: [group16][176 used]
  __shared__ float rawR[176];
  __shared__ float smu[160];
  __shared__ float dq[12];
  __shared__ float smuC[160];
  __shared__ float myY[3];
  __shared__ float sredK[4][15];
  __shared__ float sXf[12];

  float* psC = ws + OFF_PC;
  float* pYM = ws + OFF_YM;
  unsigned long long* flags = (unsigned long long*)(ws + OFF_FLAG);

  int tid = threadIdx.x;
  int blk = blockIdx.x;
  int side = blk >> 4;              // pair (b, 16+b): same XCD (b%8 == (16+b)%8)
  int b = blk & 15;
  int grp = tid >> 4;               // 16 groups of 16 lanes
  bool rep = (tid & 15) == 0;
  const float SC = 0.57735026918962584f;   // 1/sqrt(3)
  const float invN = 1.0f / N_;
  const float Nf = (float)N_;

  // ---- weights -> LDS ----
  for (int i = tid; i < SW_TOT; i += 256) {
    float v;
    if (i < 192)       v = W_in[i];
    else if (i < 204)  v = b_in[i - 192];
    else if (i < 636)  v = Wqkv_s[i - 204];
    else if (i < 672)  v = bqkv_s[i - 636];
    else if (i < 816)  v = Wo_s[i - 672];
    else if (i < 828)  v = bo_s[i - 816];
    else if (i < 1260) v = Wqkv_c[i - 828];
    else if (i < 1296) v = bqkv_c[i - 1260];
    else if (i < 1440) v = Wo_c[i - 1296];
    else if (i < 1452) v = bo_c[i - 1440];
    else if (i < 1488) v = W_out[i - 1452];
    else               v = b_out[i - 1488];
    sw[i] = v;
  }
  const float* src = side ? yo : xo;
  __syncthreads();

  // ================= Phase A: xi -> LDS, feature sums, raw k/v moments =================
  float xs[F_];
#pragma unroll
  for (int f = 0; f < F_; f++) xs[f] = 0.f;
  for (int p = 0; p < 4; p++) {
    int tok = p * 256 + tid;
    float xv[F_];
    {
      const float4* p0 = (const float4*)(src + ((size_t)b * N_ + tok) * F_);
#pragma unroll
      for (int q = 0; q < 4; q++) {
        float4 v = p0[q];
        xv[4*q+0]=v.x; xv[4*q+1]=v.y; xv[4*q+2]=v.z; xv[4*q+3]=v.w;
      }
    }
    if (!side) {
      x3buf[tok*3+0] = xv[0]; x3buf[tok*3+1] = xv[1]; x3buf[tok*3+2] = xv[2];
    }
#pragma unroll
    for (int f = 0; f < F_; f++) xs[f] += xv[f];
    float xi[E_];
#pragma unroll
    for (int e = 0; e < E_; e++) {
      float s = sw[SW_BIN + e];
#pragma unroll
      for (int f = 0; f < F_; f++) s = fmaf(xv[f], sw[SW_WIN + e*F_ + f], s);
      xi[e] = s;
    }
#pragma unroll
    for (int j4 = 0; j4 < 3; j4++)
      *(float4*)&xibuf[tok*12 + j4*4] =
        make_float4(xi[j4*4], xi[j4*4+1], xi[j4*4+2], xi[j4*4+3]);
  }
  // head-outer raw k/v moments (read xi back from LDS, own slots)
#pragma unroll
  for (int h = 0; h < H_; h++) {
    float m[40];
#pragma unroll
    for (int j = 0; j < 40; j++) m[j] = 0.f;
    for (int p = 0; p < 4; p++) {
      int tok = p * 256 + tid;
      float xi[E_];
#pragma unroll
      for (int j4 = 0; j4 < 3; j4++) {
        float4 v = *(float4*)&xibuf[tok*12 + j4*4];
        xi[j4*4]=v.x; xi[j4*4+1]=v.y; xi[j4*4+2]=v.z; xi[j4*4+3]=v.w;
      }
      float kv[6];
#pragma unroll
      for (int d = 0; d < 6; d++) {
        int o = 12 + (d/3)*12 + h*3 + (d%3);
        float s = sw[SW_BQKVS + o];
#pragma unroll
        for (int e = 0; e < E_; e++) s = fmaf(xi[e], sw[SW_WQKVS + o*E_ + e], s);
        kv[d] = s;
      }
      mom_accum(kv[0], kv[1], kv[2], kv[3], kv[4], kv[5], m);
    }
#pragma unroll
    for (int j = 0; j < 39; j++) {
      m[j] += __shfl_xor(m[j], 1);
      m[j] += __shfl_xor(m[j], 2);
      m[j] += __shfl_xor(m[j], 4);
      m[j] += __shfl_xor(m[j], 8);
    }
    if (rep) {
#pragma unroll
      for (int j4 = 0; j4 < 10; j4++)
        *(float4*)&red[grp*184 + h*40 + j4*4] =
          make_float4(m[j4*4], m[j4*4+1], m[j4*4+2], m[j4*4+3]);
    }
  }
  {
#pragma unroll
    for (int f = 0; f < F_; f++) {
      xs[f] += __shfl_xor(xs[f], 1);
      xs[f] += __shfl_xor(xs[f], 2);
      xs[f] += __shfl_xor(xs[f], 4);
      xs[f] += __shfl_xor(xs[f], 8);
    }
    if (rep) {
#pragma unroll
      for (int j4 = 0; j4 < 4; j4++)
        *(float4*)&red[grp*184 + 160 + j4*4] =
          make_float4(xs[j4*4], xs[j4*4+1], xs[j4*4+2], xs[j4*4+3]);
    }
  }
  __syncthreads();
  if (tid < 176) {
    float a = 0.f;
#pragma unroll
    for (int g = 0; g < 16; g++) a += red[g*184 + tid];
    rawR[tid] = a;
  }
  __syncthreads();

  // ---- shifted-moment correction (own side), tid 0..3 = head ----
  if (tid < H_) {
    int h = tid;
    float del[E_];
#pragma unroll
    for (int e = 0; e < E_; e++) {
      float s = 0.f;
#pragma unroll
      for (int f = 0; f < F_; f++) s = fmaf(rawR[160+f], sw[SW_WIN + e*F_ + f], s);
      del[e] = s * invN;
    }
    float A[3], G[3];
#pragma unroll
    for (int d = 0; d < 3; d++) {
      float sq=0.f, sk=0.f, sv=0.f;
#pragma unroll
      for (int e = 0; e < E_; e++) {
        sq = fmaf(del[e], sw[SW_WQKVS + (h*3+d)*E_ + e], sq);
        sk = fmaf(del[e], sw[SW_WQKVS + (12 + h*3+d)*E_ + e], sk);
        sv = fmaf(del[e], sw[SW_WQKVS + (24 + h*3+d)*E_ + e], sv);
      }
      dq[h*3+d] = sq; A[d] = sk; G[d] = sv;
    }
    const float* R = &rawR[h*40];
    float S[39];
#pragma unroll
    for (int i = 0; i < 3; i++) S[i] = R[i] - Nf*A[i];
    const int PI[6] = {0,1,2,0,0,1}, PJ[6] = {0,1,2,1,2,2};
#pragma unroll
    for (int p = 0; p < 6; p++) {
      int i = PI[p], j = PJ[p];
      S[3+p] = R[3+p] - A[i]*R[j] - A[j]*R[i] + Nf*A[i]*A[j];
    }
#pragma unroll
    for (int cc = 0; cc < 3; cc++) S[9+cc] = R[9+cc] - Nf*G[cc];
#pragma unroll
    for (int i = 0; i < 3; i++)
#pragma unroll
      for (int cc = 0; cc < 3; cc++)
        S[12+i*3+cc] = R[12+i*3+cc] - A[i]*R[9+cc] - G[cc]*R[i] + Nf*A[i]*G[cc];
#pragma unroll
    for (int p = 0; p < 6; p++) {
      int i = PI[p], j = PJ[p];
#pragma unroll
      for (int cc = 0; cc < 3; cc++) {
        S[21+p*3+cc] = R[21+p*3+cc]
                     - A[i]*R[12+j*3+cc] - A[j]*R[12+i*3+cc]
                     - G[cc]*R[3+p]
                     + A[i]*A[j]*R[9+cc]
                     + A[i]*G[cc]*R[j] + A[j]*G[cc]*R[i]
                     - Nf*A[i]*A[j]*G[cc];
      }
    }
#pragma unroll
    for (int j = 0; j < 39; j++) smu[h*40+j] = S[j] * mom_scale(j);
    smu[h*40+39] = 0.f;
  }
  __syncthreads();

  // ================= Phase B: self-attn chain per token (xi -> qc/i2, in place) ========
  for (int p = 0; p < 4; p++) {
    int tok = p * 256 + tid;
    float xi[E_];
#pragma unroll
    for (int j4 = 0; j4 < 3; j4++) {
      float4 v = *(float4*)&xibuf[tok*12 + j4*4];
      xi[j4*4]=v.x; xi[j4*4+1]=v.y; xi[j4*4+2]=v.z; xi[j4*4+3]=v.w;
    }
    float attn[E_];
#pragma unroll
    for (int h = 0; h < H_; h++) {
      float q[3];
#pragma unroll
      for (int d = 0; d < 3; d++) {
        int o = h*3 + d;
        float s = sw[SW_BQKVS + o];
#pragma unroll
        for (int e = 0; e < E_; e++) s = fmaf(xi[e], sw[SW_WQKVS + o*E_ + e], s);
        q[d] = s;
      }
      attn_eval(&smu[h*40], (q[0]-dq[h*3+0])*SC, (q[1]-dq[h*3+1])*SC,
                (q[2]-dq[h*3+2])*SC, &attn[h*3]);
    }
    float i2[E_];
#pragma unroll
    for (int e = 0; e < E_; e++) {
      float s = sw[SW_BOS + e];
#pragma unroll
      for (int j = 0; j < E_; j++) s = fmaf(attn[j], sw[SW_WOS + e*E_ + j], s);
      i2[e] = s;
    }
    float nv[E_];
    if (!side) {                    // x: cross-q
#pragma unroll
      for (int o = 0; o < 12; o++) {
        float s = sw[SW_BQKVC + o];
#pragma unroll
        for (int e = 0; e < E_; e++) s = fmaf(i2[e], sw[SW_WQKVC + o*E_ + e], s);
        nv[o] = s;
      }
    } else {                        // y: keep i2 (cross k/v computed head-outer next)
#pragma unroll
      for (int e = 0; e < E_; e++) nv[e] = i2[e];
    }
#pragma unroll
    for (int j4 = 0; j4 < 3; j4++)
      *(float4*)&xibuf[tok*12 + j4*4] =
        make_float4(nv[j4*4], nv[j4*4+1], nv[j4*4+2], nv[j4*4+3]);
  }

  if (side) {
    // ---- y: cross k/v moments (head-outer over i2 in LDS) -> publish ----
#pragma unroll
    for (int h = 0; h < H_; h++) {
      float m[40];
#pragma unroll
      for (int j = 0; j < 40; j++) m[j] = 0.f;
      for (int p = 0; p < 4; p++) {
        int tok = p * 256 + tid;
        float i2[E_];
#pragma unroll
        for (int j4 = 0; j4 < 3; j4++) {
          float4 v = *(float4*)&xibuf[tok*12 + j4*4];
          i2[j4*4]=v.x; i2[j4*4+1]=v.y; i2[j4*4+2]=v.z; i2[j4*4+3]=v.w;
        }
        float kv[6];
#pragma unroll
        for (int d = 0; d < 6; d++) {
          int o = 12 + (d/3)*12 + h*3 + (d%3);
          float s = sw[SW_BQKVC + o];
#pragma unroll
          for (int e = 0; e < E_; e++) s = fmaf(i2[e], sw[SW_WQKVC + o*E_ + e], s);
          kv[d] = s;
        }
        mom_accum(kv[0], kv[1], kv[2], kv[3], kv[4], kv[5], m);
      }
#pragma unroll
      for (int j = 0; j < 39; j++) {
        m[j] += __shfl_xor(m[j], 1);
        m[j] += __shfl_xor(m[j], 2);
        m[j] += __shfl_xor(m[j], 4);
        m[j] += __shfl_xor(m[j], 8);
      }
      if (rep) {
#pragma unroll
        for (int j4 = 0; j4 < 10; j4++)
          *(float4*)&red[grp*184 + h*40 + j4*4] =
            make_float4(m[j4*4], m[j4*4+1], m[j4*4+2], m[j4*4+3]);
      }
    }
    __syncthreads();
    if (tid < 160) {
      float a = 0.f;
#pragma unroll
      for (int g = 0; g < 16; g++) a += red[g*184 + tid];
      data_store(&psC[(size_t)b*160 + tid], a);
    } else if (tid < 163) {
      data_store(&pYM[b*3 + (tid - 160)], rawR[160 + (tid - 160)]);
    }
    __syncthreads();                // drains vmcnt for all waves
    if (tid == 0) flag_set(&flags[b], TAG_C);
    return;                         // y block done
  }

  // ================= x: wait for y, load cross moments =================
  if (tid == 0) flag_wait(&flags[b], TAG_C);
  __syncthreads();
  if (tid < 160) {
    int j = tid - (tid/40)*40;
    smuC[tid] = data_load(&psC[(size_t)b*160 + tid]) * mom_scale(j);
  } else if (tid < 163) {
    myY[tid-160] = data_load(&pYM[b*3 + (tid-160)]) * invN;
  }
  __syncthreads();

  // ================= Phase C: cross-attn + Kabsch stats =================
  float mx0 = rawR[160]*invN, mx1 = rawR[161]*invN, mx2 = rawR[162]*invN;
  {
    float st[15];
#pragma unroll
    for (int i = 0; i < 15; i++) st[i] = 0.f;
    for (int p = 0; p < 4; p++) {
      int tok = p * 256 + tid;
      float qc[E_];
#pragma unroll
      for (int j4 = 0; j4 < 3; j4++) {
        float4 v = *(float4*)&xibuf[tok*12 + j4*4];
        qc[j4*4]=v.x; qc[j4*4+1]=v.y; qc[j4*4+2]=v.z; qc[j4*4+3]=v.w;
      }
      float attn[E_];
#pragma unroll
      for (int h = 0; h < H_; h++)
        attn_eval(&smuC[h*40], qc[h*3+0]*SC, qc[h*3+1]*SC, qc[h*3+2]*SC, &attn[h*3]);
      float c12[E_];
#pragma unroll
      for (int e = 0; e < E_; e++) {
        float s = sw[SW_BOC + e];
#pragma unroll
        for (int j = 0; j < E_; j++) s = fmaf(attn[j], sw[SW_WOC + e*E_ + j], s);
        c12[e] = s;
      }
      float co[3];
#pragma unroll
      for (int k = 0; k < 3; k++) {
        float s = sw[SW_BOUT + k];
#pragma unroll
        for (int e = 0; e < E_; e++) s = fmaf(c12[e], sw[SW_WOUT + k*E_ + e], s);
        co[k] = s;
      }
      float x0 = x3buf[tok*3+0] - mx0;
      float x1 = x3buf[tok*3+1] - mx1;
      float x2 = x3buf[tok*3+2] - mx2;
      float A0 = co[0]+x0, A1 = co[1]+x1, A2 = co[2]+x2;
      st[0]+=co[0]; st[1]+=co[1]; st[2]+=co[2];
      st[3]+=x0; st[4]+=x1; st[5]+=x2;
      st[6]=fmaf(x0,A0,st[6]);  st[7]=fmaf(x0,A1,st[7]);  st[8]=fmaf(x0,A2,st[8]);
      st[9]=fmaf(x1,A0,st[9]);  st[10]=fmaf(x1,A1,st[10]); st[11]=fmaf(x1,A2,st[11]);
      st[12]=fmaf(x2,A0,st[12]); st[13]=fmaf(x2,A1,st[13]); st[14]=fmaf(x2,A2,st[14]);
    }
#pragma unroll
    for (int i = 0; i < 15; i++) {
      st[i] += __shfl_down(st[i], 32); st[i] += __shfl_down(st[i], 16);
      st[i] += __shfl_down(st[i], 8);  st[i] += __shfl_down(st[i], 4);
      st[i] += __shfl_down(st[i], 2);  st[i] += __shfl_down(st[i], 1);
    }
    if ((tid & 63) == 0) {
      int wv = tid >> 6;
#pragma unroll
      for (int i = 0; i < 15; i++) sredK[wv][i] = st[i];
    }
  }
  __syncthreads();

  // ================= Phase D: polar (wave 0) + transform =================
  if (tid < 64) {
    float s[15];
#pragma unroll
    for (int i = 0; i < 15; i++) s[i] = sredK[0][i] + sredK[1][i] + sredK[2][i] + sredK[3][i];
    float cB[3] = { s[3]*invN, s[4]*invN, s[5]*invN };
    float cA[3] = { (s[0]+s[3])*invN, (s[1]+s[4])*invN, (s[2]+s[5])*invN };
    float X[9];
#pragma unroll
    for (int i = 0; i < 3; i++)
#pragma unroll
      for (int j = 0; j < 3; j++)
        X[i*3+j] = s[6 + i*3 + j] - Nf * cB[i] * cA[j];
    float fn = 0.f;
#pragma unroll
    for (int i = 0; i < 9; i++) fn += X[i]*X[i];
    float scl = rsqrtf(fn);
#pragma unroll
    for (int i = 0; i < 9; i++) X[i] *= scl;
    for (int it = 0; it < 24; it++) {
      float c00 =  X[4]*X[8]-X[5]*X[7];
      float c01 = -(X[3]*X[8]-X[5]*X[6]);
      float c02 =  X[3]*X[7]-X[4]*X[6];
      float c10 = -(X[1]*X[8]-X[2]*X[7]);
      float c11 =  X[0]*X[8]-X[2]*X[6];
      float c12_= -(X[0]*X[7]-X[1]*X[6]);
      float c20 =  X[1]*X[5]-X[2]*X[4];
      float c21 = -(X[0]*X[5]-X[2]*X[3]);
      float c22 =  X[0]*X[4]-X[1]*X[3];
      float det = X[0]*c00 + X[1]*c01 + X[2]*c02;
      float id = 0.5f / det;
      X[0]=0.5f*X[0]+c00*id; X[1]=0.5f*X[1]+c01*id; X[2]=0.5f*X[2]+c02*id;
      X[3]=0.5f*X[3]+c10*id; X[4]=0.5f*X[4]+c11*id; X[5]=0.5f*X[5]+c12_*id;
      X[6]=0.5f*X[6]+c20*id; X[7]=0.5f*X[7]+c21*id; X[8]=0.5f*X[8]+c22*id;
    }
    if (tid == 0) {
#pragma unroll
      for (int i = 0; i < 9; i++) sXf[i] = X[i];
#pragma unroll
      for (int k = 0; k < 3; k++)
        sXf[9+k] = cA[k] - (cB[0]*X[k] + cB[1]*X[3+k] + cB[2]*X[6+k]) + myY[k];
    }
  }
  __syncthreads();
  {
    float X0=sXf[0], X1=sXf[1], X2=sXf[2], X3=sXf[3], X4=sXf[4], X5=sXf[5],
          X6=sXf[6], X7=sXf[7], X8=sXf[8], t0=sXf[9], t1=sXf[10], t2=sXf[11];
    for (int p = 0; p < 4; p++) {
      int tok = p * 256 + tid;
      float x0 = x3buf[tok*3+0] - mx0;
      float x1 = x3buf[tok*3+1] - mx1;
      float x2 = x3buf[tok*3+2] - mx2;
      size_t t = (size_t)b * N_ + tok;
      out[t*3+0] = fmaf(x0, X0, fmaf(x1, X3, fmaf(x2, X6, t0)));
      out[t*3+1] = fmaf(x0, X1, fmaf(x1, X4, fmaf(x2, X7, t1)));
      out[t*3+2] = fmaf(x0, X2, fmaf(x1, X5, fmaf(x2, X8, t2)));
    }
  }
}

extern "C" void kernel_launch(void* const* d_in, const int* in_sizes, int n_in,
                              void* d_out, int out_size, void* d_ws, size_t ws_size,
                              hipStream_t stream) {
  const float* x_orig = (const float*)d_in[0];
  const float* y_orig = (const float*)d_in[1];
  const float* W_in   = (const float*)d_in[2];
  const float* b_in   = (const float*)d_in[3];
  const float* Wqkv_s = (const float*)d_in[4];
  const float* bqkv_s = (const float*)d_in[5];
  const float* Wo_s   = (const float*)d_in[6];
  const float* bo_s   = (const float*)d_in[7];
  const float* Wqkv_c = (const float*)d_in[8];
  const float* bqkv_c = (const float*)d_in[9];
  const float* Wo_c   = (const float*)d_in[10];
  const float* bo_c   = (const float*)d_in[11];
  const float* W_out  = (const float*)d_in[12];
  const float* b_out  = (const float*)d_in[13];
  float* ws = (float*)d_ws;

  k_all<<<32, 256, 0, stream>>>(x_orig, y_orig, W_in, b_in, Wqkv_s, bqkv_s,
                                Wo_s, bo_s, Wqkv_c, bqkv_c, Wo_c, bo_c,
                                W_out, b_out, ws, (float*)d_out);
}

// Round 10
// 127.140 us; speedup vs baseline: 1.9811x; 1.0668x over previous
//
#include <hip/hip_runtime.h>

#define B_ 16
#define N_ 1024
#define F_ 16
#define E_ 12
#define H_ 4

// 32 blocks x 256 threads: block (side,b) owns 1024 tokens of that side/batch.
// Per-token intermediates staged in LDS (xibuf); all projection loops process
// 2-token pairs so each LDS weight read is amortized over 2 FMA-dots.
// Single cross-block hop: y-block publishes cross moments + y-mean -> x-block.
// ws: psC[16][160] | ymean[16][3] | flags[16] u64
#define OFF_PC 0
#define OFF_YM 2560
#define OFF_FLAG 2608   // float offset; byte 10432, 8-aligned
#define TAG_C 0x51A7E0C5ull

// shared-weight offsets
#define SW_WIN   0      // 192
#define SW_BIN   192    // 12
#define SW_WQKVS 204    // 432
#define SW_BQKVS 636    // 36
#define SW_WOS   672    // 144
#define SW_BOS   816    // 12
#define SW_WQKVC 828    // 432
#define SW_BQKVC 1260   // 36
#define SW_WOC   1296   // 144
#define SW_BOC   1440   // 12
#define SW_WOUT  1452   // 36
#define SW_BOUT  1488   // 3
#define SW_TOT   1491

// moment layout per head (39 used, stride 40):
// [0:3]=Sum k | [3:9]=Sum kk (00,11,22,01,02,12) | [9:12]=Sum v
// [12:21]=Sum k_i v_c | [21:39]=Sum kk_pair v_c

__device__ __forceinline__ void data_store(float* p, float v) {
  __hip_atomic_store((unsigned*)p, __float_as_uint(v),
                     __ATOMIC_RELAXED, __HIP_MEMORY_SCOPE_AGENT);
}
__device__ __forceinline__ float data_load(const float* p) {
  unsigned u = __hip_atomic_load((const unsigned*)p,
                                 __ATOMIC_RELAXED, __HIP_MEMORY_SCOPE_AGENT);
  return __uint_as_float(u);
}
__device__ __forceinline__ void flag_set(unsigned long long* f, unsigned long long tag) {
  __hip_atomic_store(f, tag, __ATOMIC_RELAXED, __HIP_MEMORY_SCOPE_AGENT);
}
__device__ __forceinline__ void flag_wait(unsigned long long* f, unsigned long long tag) {
  while (__hip_atomic_load(f, __ATOMIC_RELAXED, __HIP_MEMORY_SCOPE_AGENT) != tag)
    __builtin_amdgcn_s_sleep(2);
  asm volatile("" ::: "memory");
}

__device__ __forceinline__ void mom_accum(float k0, float k1, float k2,
                                          float v0, float v1, float v2, float* m) {
  m[0]+=k0; m[1]+=k1; m[2]+=k2;
  float s00=k0*k0, s11=k1*k1, s22=k2*k2, s01=k0*k1, s02=k0*k2, s12=k1*k2;
  m[3]+=s00; m[4]+=s11; m[5]+=s22; m[6]+=s01; m[7]+=s02; m[8]+=s12;
  m[9]+=v0; m[10]+=v1; m[11]+=v2;
  m[12]+=k0*v0; m[13]+=k0*v1; m[14]+=k0*v2;
  m[15]+=k1*v0; m[16]+=k1*v1; m[17]+=k1*v2;
  m[18]+=k2*v0; m[19]+=k2*v1; m[20]+=k2*v2;
  m[21]+=s00*v0; m[22]+=s00*v1; m[23]+=s00*v2;
  m[24]+=s11*v0; m[25]+=s11*v1; m[26]+=s11*v2;
  m[27]+=s22*v0; m[28]+=s22*v1; m[29]+=s22*v2;
  m[30]+=s01*v0; m[31]+=s01*v1; m[32]+=s01*v2;
  m[33]+=s02*v0; m[34]+=s02*v1; m[35]+=s02*v2;
  m[36]+=s12*v0; m[37]+=s12*v1; m[38]+=s12*v2;
}

// dual-token eval: each mu element read ONCE for both tokens
__device__ __forceinline__ void attn_eval2(const float* __restrict__ mu,
                                           const float* pa, const float* pb,
                                           float* oa, float* ob) {
  float A0=pa[0],A1=pa[1],A2=pa[2], B0=pb[0],B1=pb[1],B2=pb[2];
  float a00=A0*A0, a11=A1*A1, a22=A2*A2, a01=A0*A1, a02=A0*A2, a12=A1*A2;
  float b00=B0*B0, b11=B1*B1, b22=B2*B2, b01=B0*B1, b02=B0*B2, b12=B1*B2;
  float da=(float)N_, db=(float)N_, w;
  w=mu[0]; da=fmaf(A0,w,da);  db=fmaf(B0,w,db);
  w=mu[1]; da=fmaf(A1,w,da);  db=fmaf(B1,w,db);
  w=mu[2]; da=fmaf(A2,w,da);  db=fmaf(B2,w,db);
  w=mu[3]; da=fmaf(a00,w,da); db=fmaf(b00,w,db);
  w=mu[4]; da=fmaf(a11,w,da); db=fmaf(b11,w,db);
  w=mu[5]; da=fmaf(a22,w,da); db=fmaf(b22,w,db);
  w=mu[6]; da=fmaf(a01,w,da); db=fmaf(b01,w,db);
  w=mu[7]; da=fmaf(a02,w,da); db=fmaf(b02,w,db);
  w=mu[8]; da=fmaf(a12,w,da); db=fmaf(b12,w,db);
  float ia = 1.0f/da, ib = 1.0f/db;
#pragma unroll
  for (int c = 0; c < 3; c++) {
    float na, nb; w=mu[9+c]; na=w; nb=w;
    w=mu[12+c]; na=fmaf(A0,w,na);  nb=fmaf(B0,w,nb);
    w=mu[15+c]; na=fmaf(A1,w,na);  nb=fmaf(B1,w,nb);
    w=mu[18+c]; na=fmaf(A2,w,na);  nb=fmaf(B2,w,nb);
    w=mu[21+c]; na=fmaf(a00,w,na); nb=fmaf(b00,w,nb);
    w=mu[24+c]; na=fmaf(a11,w,na); nb=fmaf(b11,w,nb);
    w=mu[27+c]; na=fmaf(a22,w,na); nb=fmaf(b22,w,nb);
    w=mu[30+c]; na=fmaf(a01,w,na); nb=fmaf(b01,w,nb);
    w=mu[33+c]; na=fmaf(a02,w,na); nb=fmaf(b02,w,nb);
    w=mu[36+c]; na=fmaf(a12,w,na); nb=fmaf(b12,w,nb);
    oa[c]=na*ia; ob[c]=nb*ib;
  }
}

__device__ __forceinline__ float mom_scale(int j) {
  return ((j >= 3 && j < 6) || (j >= 21 && j < 30)) ? 0.5f : 1.0f;
}

#define LOAD12(dst, tok) { \
  float4 v0_ = *(float4*)&xibuf[(tok)*12]; \
  float4 v1_ = *(float4*)&xibuf[(tok)*12+4]; \
  float4 v2_ = *(float4*)&xibuf[(tok)*12+8]; \
  dst[0]=v0_.x; dst[1]=v0_.y; dst[2]=v0_.z; dst[3]=v0_.w; \
  dst[4]=v1_.x; dst[5]=v1_.y; dst[6]=v1_.z; dst[7]=v1_.w; \
  dst[8]=v2_.x; dst[9]=v2_.y; dst[10]=v2_.z; dst[11]=v2_.w; }
#define STORE12(src, tok) { \
  *(float4*)&xibuf[(tok)*12]   = make_float4(src[0],src[1],src[2],src[3]); \
  *(float4*)&xibuf[(tok)*12+4] = make_float4(src[4],src[5],src[6],src[7]); \
  *(float4*)&xibuf[(tok)*12+8] = make_float4(src[8],src[9],src[10],src[11]); }

__global__ __launch_bounds__(256, 1)
void k_all(const float* __restrict__ xo, const float* __restrict__ yo,
           const float* __restrict__ W_in, const float* __restrict__ b_in,
           const float* __restrict__ Wqkv_s, const float* __restrict__ bqkv_s,
           const float* __restrict__ Wo_s, const float* __restrict__ bo_s,
           const float* __restrict__ Wqkv_c, const float* __restrict__ bqkv_c,
           const float* __restrict__ Wo_c, const float* __restrict__ bo_c,
           const float* __restrict__ W_out, const float* __restrict__ b_out,
           float* __restrict__ ws, float* __restrict__ out) {
  __shared__ float sw[SW_TOT];
  __shared__ float xibuf[1024 * 12];  // 48 KB: xi (A) -> qc (x) / i2 (y)
  __shared__ float x3buf[1024 * 3];   // 12 KB: raw x[:, :3] (x blocks)
  __shared__ float red[16 * 184];     // 11.8 KB
  __shared__ float rawR[176];
  __shared__ float smu[160];
  __shared__ float dq[12];
  __shared__ float smuC[160];
  __shared__ float myY[3];
  __shared__ float sredK[4][15];
  __shared__ float sXf[12];

  float* psC = ws + OFF_PC;
  float* pYM = ws + OFF_YM;
  unsigned long long* flags = (unsigned long long*)(ws + OFF_FLAG);

  int tid = threadIdx.x;
  int blk = blockIdx.x;
  int side = blk >> 4;              // pair (b, 16+b): same XCD
  int b = blk & 15;
  int grp = tid >> 4;
  bool rep = (tid & 15) == 0;
  const float SC = 0.57735026918962584f;   // 1/sqrt(3)
  const float invN = 1.0f / N_;
  const float Nf = (float)N_;

  // ---- weights -> LDS ----
  for (int i = tid; i < SW_TOT; i += 256) {
    float v;
    if (i < 192)       v = W_in[i];
    else if (i < 204)  v = b_in[i - 192];
    else if (i < 636)  v = Wqkv_s[i - 204];
    else if (i < 672)  v = bqkv_s[i - 636];
    else if (i < 816)  v = Wo_s[i - 672];
    else if (i < 828)  v = bo_s[i - 816];
    else if (i < 1260) v = Wqkv_c[i - 828];
    else if (i < 1296) v = bqkv_c[i - 1260];
    else if (i < 1440) v = Wo_c[i - 1296];
    else if (i < 1452) v = bo_c[i - 1440];
    else if (i < 1488) v = W_out[i - 1452];
    else               v = b_out[i - 1488];
    sw[i] = v;
  }
  const float* src = side ? yo : xo;
  __syncthreads();

  // ================= Phase A-proj: xi -> LDS (2-token pairs) =================
  float xs[F_];
#pragma unroll
  for (int f = 0; f < F_; f++) xs[f] = 0.f;
#pragma unroll
  for (int p = 0; p < 2; p++) {
    int ta = p*512 + tid, tb = ta + 256;
    float xva[F_], xvb[F_];
    {
      const float4* pa = (const float4*)(src + ((size_t)b * N_ + ta) * F_);
      const float4* pb = (const float4*)(src + ((size_t)b * N_ + tb) * F_);
#pragma unroll
      for (int q = 0; q < 4; q++) {
        float4 va = pa[q], vb = pb[q];
        xva[4*q+0]=va.x; xva[4*q+1]=va.y; xva[4*q+2]=va.z; xva[4*q+3]=va.w;
        xvb[4*q+0]=vb.x; xvb[4*q+1]=vb.y; xvb[4*q+2]=vb.z; xvb[4*q+3]=vb.w;
      }
    }
    if (!side) {
      x3buf[ta*3+0]=xva[0]; x3buf[ta*3+1]=xva[1]; x3buf[ta*3+2]=xva[2];
      x3buf[tb*3+0]=xvb[0]; x3buf[tb*3+1]=xvb[1]; x3buf[tb*3+2]=xvb[2];
    }
#pragma unroll
    for (int f = 0; f < F_; f++) xs[f] += xva[f] + xvb[f];
    float xia[E_], xib[E_];
#pragma unroll
    for (int e = 0; e < E_; e++) {
      const float* wr = &sw[SW_WIN + e*F_];
      float sa = sw[SW_BIN + e], sb = sa;
#pragma unroll
      for (int f = 0; f < F_; f++) { float we = wr[f]; sa=fmaf(xva[f],we,sa); sb=fmaf(xvb[f],we,sb); }
      xia[e] = sa; xib[e] = sb;
    }
    STORE12(xia, ta); STORE12(xib, tb);
  }

  // ---- Phase A-moments: raw self k/v moments (pairs, weight reads amortized) ----
#pragma unroll
  for (int h = 0; h < H_; h++) {
    float m[40];
#pragma unroll
    for (int j = 0; j < 40; j++) m[j] = 0.f;
#pragma unroll
    for (int p = 0; p < 2; p++) {
      int ta = p*512 + tid, tb = ta + 256;
      float xa[E_], xb[E_];
      LOAD12(xa, ta); LOAD12(xb, tb);
      float ka[6], kb[6];
#pragma unroll
      for (int d = 0; d < 6; d++) {
        int o = 12 + (d/3)*12 + h*3 + (d%3);
        const float* wr = &sw[SW_WQKVS + o*E_];
        float sa = sw[SW_BQKVS + o], sb = sa;
#pragma unroll
        for (int e = 0; e < E_; e++) { float we = wr[e]; sa=fmaf(xa[e],we,sa); sb=fmaf(xb[e],we,sb); }
        ka[d]=sa; kb[d]=sb;
      }
      mom_accum(ka[0],ka[1],ka[2],ka[3],ka[4],ka[5], m);
      mom_accum(kb[0],kb[1],kb[2],kb[3],kb[4],kb[5], m);
    }
#pragma unroll
    for (int j = 0; j < 39; j++) {
      m[j] += __shfl_xor(m[j], 1);
      m[j] += __shfl_xor(m[j], 2);
      m[j] += __shfl_xor(m[j], 4);
      m[j] += __shfl_xor(m[j], 8);
    }
    if (rep) {
#pragma unroll
      for (int j4 = 0; j4 < 10; j4++)
        *(float4*)&red[grp*184 + h*40 + j4*4] =
          make_float4(m[j4*4], m[j4*4+1], m[j4*4+2], m[j4*4+3]);
    }
  }
  {
#pragma unroll
    for (int f = 0; f < F_; f++) {
      xs[f] += __shfl_xor(xs[f], 1);
      xs[f] += __shfl_xor(xs[f], 2);
      xs[f] += __shfl_xor(xs[f], 4);
      xs[f] += __shfl_xor(xs[f], 8);
    }
    if (rep) {
#pragma unroll
      for (int j4 = 0; j4 < 4; j4++)
        *(float4*)&red[grp*184 + 160 + j4*4] =
          make_float4(xs[j4*4], xs[j4*4+1], xs[j4*4+2], xs[j4*4+3]);
    }
  }
  __syncthreads();
  if (tid < 176) {
    float a = 0.f;
#pragma unroll
    for (int g = 0; g < 16; g++) a += red[g*184 + tid];
    rawR[tid] = a;
  }
  __syncthreads();

  // ---- shifted-moment correction (own side), tid 0..3 = head ----
  if (tid < H_) {
    int h = tid;
    float del[E_];
#pragma unroll
    for (int e = 0; e < E_; e++) {
      float s = 0.f;
#pragma unroll
      for (int f = 0; f < F_; f++) s = fmaf(rawR[160+f], sw[SW_WIN + e*F_ + f], s);
      del[e] = s * invN;
    }
    float A[3], G[3];
#pragma unroll
    for (int d = 0; d < 3; d++) {
      float sq=0.f, sk=0.f, sv=0.f;
#pragma unroll
      for (int e = 0; e < E_; e++) {
        sq = fmaf(del[e], sw[SW_WQKVS + (h*3+d)*E_ + e], sq);
        sk = fmaf(del[e], sw[SW_WQKVS + (12 + h*3+d)*E_ + e], sk);
        sv = fmaf(del[e], sw[SW_WQKVS + (24 + h*3+d)*E_ + e], sv);
      }
      dq[h*3+d] = sq; A[d] = sk; G[d] = sv;
    }
    const float* R = &rawR[h*40];
    float S[39];
#pragma unroll
    for (int i = 0; i < 3; i++) S[i] = R[i] - Nf*A[i];
    const int PI[6] = {0,1,2,0,0,1}, PJ[6] = {0,1,2,1,2,2};
#pragma unroll
    for (int p = 0; p < 6; p++) {
      int i = PI[p], j = PJ[p];
      S[3+p] = R[3+p] - A[i]*R[j] - A[j]*R[i] + Nf*A[i]*A[j];
    }
#pragma unroll
    for (int cc = 0; cc < 3; cc++) S[9+cc] = R[9+cc] - Nf*G[cc];
#pragma unroll
    for (int i = 0; i < 3; i++)
#pragma unroll
      for (int cc = 0; cc < 3; cc++)
        S[12+i*3+cc] = R[12+i*3+cc] - A[i]*R[9+cc] - G[cc]*R[i] + Nf*A[i]*G[cc];
#pragma unroll
    for (int p = 0; p < 6; p++) {
      int i = PI[p], j = PJ[p];
#pragma unroll
      for (int cc = 0; cc < 3; cc++) {
        S[21+p*3+cc] = R[21+p*3+cc]
                     - A[i]*R[12+j*3+cc] - A[j]*R[12+i*3+cc]
                     - G[cc]*R[3+p]
                     + A[i]*A[j]*R[9+cc]
                     + A[i]*G[cc]*R[j] + A[j]*G[cc]*R[i]
                     - Nf*A[i]*A[j]*G[cc];
      }
    }
#pragma unroll
    for (int j = 0; j < 39; j++) smu[h*40+j] = S[j] * mom_scale(j);
    smu[h*40+39] = 0.f;
  }
  __syncthreads();

  // ================= Phase B: self-attn chain (2-token pairs, in-place) ========
#pragma unroll
  for (int p = 0; p < 2; p++) {
    int ta = p*512 + tid, tb = ta + 256;
    float xa[E_], xb[E_];
    LOAD12(xa, ta); LOAD12(xb, tb);
    float ata[E_], atb[E_];
#pragma unroll
    for (int h = 0; h < H_; h++) {
      float qa[3], qb[3];
#pragma unroll
      for (int d = 0; d < 3; d++) {
        int o = h*3 + d;
        const float* wr = &sw[SW_WQKVS + o*E_];
        float sa = sw[SW_BQKVS + o], sb = sa;
#pragma unroll
        for (int e = 0; e < E_; e++) { float we = wr[e]; sa=fmaf(xa[e],we,sa); sb=fmaf(xb[e],we,sb); }
        qa[d]=sa; qb[d]=sb;
      }
      float pa[3] = { (qa[0]-dq[h*3+0])*SC, (qa[1]-dq[h*3+1])*SC, (qa[2]-dq[h*3+2])*SC };
      float pb[3] = { (qb[0]-dq[h*3+0])*SC, (qb[1]-dq[h*3+1])*SC, (qb[2]-dq[h*3+2])*SC };
      attn_eval2(&smu[h*40], pa, pb, &ata[h*3], &atb[h*3]);
    }
    float i2a[E_], i2b[E_];
#pragma unroll
    for (int e = 0; e < E_; e++) {
      const float* wr = &sw[SW_WOS + e*E_];
      float sa = sw[SW_BOS + e], sb = sa;
#pragma unroll
      for (int j = 0; j < E_; j++) { float we = wr[j]; sa=fmaf(ata[j],we,sa); sb=fmaf(atb[j],we,sb); }
      i2a[e]=sa; i2b[e]=sb;
    }
    if (!side) {                    // x: cross-q
      float nva[E_], nvb[E_];
#pragma unroll
      for (int o = 0; o < 12; o++) {
        const float* wr = &sw[SW_WQKVC + o*E_];
        float sa = sw[SW_BQKVC + o], sb = sa;
#pragma unroll
        for (int e = 0; e < E_; e++) { float we = wr[e]; sa=fmaf(i2a[e],we,sa); sb=fmaf(i2b[e],we,sb); }
        nva[o]=sa; nvb[o]=sb;
      }
      STORE12(nva, ta); STORE12(nvb, tb);
    } else {                        // y: keep i2 for cross-moment pass
      STORE12(i2a, ta); STORE12(i2b, tb);
    }
  }

  if (side) {
    // ---- y: cross k/v moments (pairs) -> publish ----
#pragma unroll
    for (int h = 0; h < H_; h++) {
      float m[40];
#pragma unroll
      for (int j = 0; j < 40; j++) m[j] = 0.f;
#pragma unroll
      for (int p = 0; p < 2; p++) {
        int ta = p*512 + tid, tb = ta + 256;
        float xa[E_], xb[E_];
        LOAD12(xa, ta); LOAD12(xb, tb);
        float ka[6], kb[6];
#pragma unroll
        for (int d = 0; d < 6; d++) {
          int o = 12 + (d/3)*12 + h*3 + (d%3);
          const float* wr = &sw[SW_WQKVC + o*E_];
          float sa = sw[SW_BQKVC + o], sb = sa;
#pragma unroll
          for (int e = 0; e < E_; e++) { float we = wr[e]; sa=fmaf(xa[e],we,sa); sb=fmaf(xb[e],we,sb); }
          ka[d]=sa; kb[d]=sb;
        }
        mom_accum(ka[0],ka[1],ka[2],ka[3],ka[4],ka[5], m);
        mom_accum(kb[0],kb[1],kb[2],kb[3],kb[4],kb[5], m);
      }
#pragma unroll
      for (int j = 0; j < 39; j++) {
        m[j] += __shfl_xor(m[j], 1);
        m[j] += __shfl_xor(m[j], 2);
        m[j] += __shfl_xor(m[j], 4);
        m[j] += __shfl_xor(m[j], 8);
      }
      if (rep) {
#pragma unroll
        for (int j4 = 0; j4 < 10; j4++)
          *(float4*)&red[grp*184 + h*40 + j4*4] =
            make_float4(m[j4*4], m[j4*4+1], m[j4*4+2], m[j4*4+3]);
      }
    }
    __syncthreads();
    if (tid < 160) {
      float a = 0.f;
#pragma unroll
      for (int g = 0; g < 16; g++) a += red[g*184 + tid];
      data_store(&psC[(size_t)b*160 + tid], a);
    } else if (tid < 163) {
      data_store(&pYM[b*3 + (tid - 160)], rawR[160 + (tid - 160)]);
    }
    __syncthreads();                // drains vmcnt for all waves
    if (tid == 0) flag_set(&flags[b], TAG_C);
    return;                         // y block done
  }

  // ================= x: wait for y, load cross moments =================
  if (tid == 0) flag_wait(&flags[b], TAG_C);
  __syncthreads();
  if (tid < 160) {
    int j = tid - (tid/40)*40;
    smuC[tid] = data_load(&psC[(size_t)b*160 + tid]) * mom_scale(j);
  } else if (tid < 163) {
    myY[tid-160] = data_load(&pYM[b*3 + (tid-160)]) * invN;
  }
  __syncthreads();

  // ================= Phase C: cross-attn + Kabsch stats (pairs) =================
  float mx0 = rawR[160]*invN, mx1 = rawR[161]*invN, mx2 = rawR[162]*invN;
  {
    float st[15];
#pragma unroll
    for (int i = 0; i < 15; i++) st[i] = 0.f;
#pragma unroll
    for (int p = 0; p < 2; p++) {
      int ta = p*512 + tid, tb = ta + 256;
      float qa[E_], qb[E_];
      LOAD12(qa, ta); LOAD12(qb, tb);
      float ata[E_], atb[E_];
#pragma unroll
      for (int h = 0; h < H_; h++) {
        float pa[3] = { qa[h*3+0]*SC, qa[h*3+1]*SC, qa[h*3+2]*SC };
        float pb[3] = { qb[h*3+0]*SC, qb[h*3+1]*SC, qb[h*3+2]*SC };
        attn_eval2(&smuC[h*40], pa, pb, &ata[h*3], &atb[h*3]);
      }
      float ca[E_], cb[E_];
#pragma unroll
      for (int e = 0; e < E_; e++) {
        const float* wr = &sw[SW_WOC + e*E_];
        float sa = sw[SW_BOC + e], sb = sa;
#pragma unroll
        for (int j = 0; j < E_; j++) { float we = wr[j]; sa=fmaf(ata[j],we,sa); sb=fmaf(atb[j],we,sb); }
        ca[e]=sa; cb[e]=sb;
      }
      float coa[3], cob[3];
#pragma unroll
      for (int k = 0; k < 3; k++) {
        const float* wr = &sw[SW_WOUT + k*E_];
        float sa = sw[SW_BOUT + k], sb = sa;
#pragma unroll
        for (int e = 0; e < E_; e++) { float we = wr[e]; sa=fmaf(ca[e],we,sa); sb=fmaf(cb[e],we,sb); }
        coa[k]=sa; cob[k]=sb;
      }
      {
        float x0 = x3buf[ta*3+0]-mx0, x1 = x3buf[ta*3+1]-mx1, x2 = x3buf[ta*3+2]-mx2;
        float A0 = coa[0]+x0, A1 = coa[1]+x1, A2 = coa[2]+x2;
        st[0]+=coa[0]; st[1]+=coa[1]; st[2]+=coa[2];
        st[3]+=x0; st[4]+=x1; st[5]+=x2;
        st[6]=fmaf(x0,A0,st[6]);  st[7]=fmaf(x0,A1,st[7]);  st[8]=fmaf(x0,A2,st[8]);
        st[9]=fmaf(x1,A0,st[9]);  st[10]=fmaf(x1,A1,st[10]); st[11]=fmaf(x1,A2,st[11]);
        st[12]=fmaf(x2,A0,st[12]); st[13]=fmaf(x2,A1,st[13]); st[14]=fmaf(x2,A2,st[14]);
      }
      {
        float x0 = x3buf[tb*3+0]-mx0, x1 = x3buf[tb*3+1]-mx1, x2 = x3buf[tb*3+2]-mx2;
        float A0 = cob[0]+x0, A1 = cob[1]+x1, A2 = cob[2]+x2;
        st[0]+=cob[0]; st[1]+=cob[1]; st[2]+=cob[2];
        st[3]+=x0; st[4]+=x1; st[5]+=x2;
        st[6]=fmaf(x0,A0,st[6]);  st[7]=fmaf(x0,A1,st[7]);  st[8]=fmaf(x0,A2,st[8]);
        st[9]=fmaf(x1,A0,st[9]);  st[10]=fmaf(x1,A1,st[10]); st[11]=fmaf(x1,A2,st[11]);
        st[12]=fmaf(x2,A0,st[12]); st[13]=fmaf(x2,A1,st[13]); st[14]=fmaf(x2,A2,st[14]);
      }
    }
#pragma unroll
    for (int i = 0; i < 15; i++) {
      st[i] += __shfl_down(st[i], 32); st[i] += __shfl_down(st[i], 16);
      st[i] += __shfl_down(st[i], 8);  st[i] += __shfl_down(st[i], 4);
      st[i] += __shfl_down(st[i], 2);  st[i] += __shfl_down(st[i], 1);
    }
    if ((tid & 63) == 0) {
      int wv = tid >> 6;
#pragma unroll
      for (int i = 0; i < 15; i++) sredK[wv][i] = st[i];
    }
  }
  __syncthreads();

  // ================= Phase D: polar (wave 0) + transform =================
  if (tid < 64) {
    float s[15];
#pragma unroll
    for (int i = 0; i < 15; i++) s[i] = sredK[0][i] + sredK[1][i] + sredK[2][i] + sredK[3][i];
    float cB[3] = { s[3]*invN, s[4]*invN, s[5]*invN };
    float cA[3] = { (s[0]+s[3])*invN, (s[1]+s[4])*invN, (s[2]+s[5])*invN };
    float X[9];
#pragma unroll
    for (int i = 0; i < 3; i++)
#pragma unroll
      for (int j = 0; j < 3; j++)
        X[i*3+j] = s[6 + i*3 + j] - Nf * cB[i] * cA[j];
    float fn = 0.f;
#pragma unroll
    for (int i = 0; i < 9; i++) fn += X[i]*X[i];
    float scl = rsqrtf(fn);
#pragma unroll
    for (int i = 0; i < 9; i++) X[i] *= scl;
    for (int it = 0; it < 24; it++) {
      float c00 =  X[4]*X[8]-X[5]*X[7];
      float c01 = -(X[3]*X[8]-X[5]*X[6]);
      float c02 =  X[3]*X[7]-X[4]*X[6];
      float c10 = -(X[1]*X[8]-X[2]*X[7]);
      float c11 =  X[0]*X[8]-X[2]*X[6];
      float c12_= -(X[0]*X[7]-X[1]*X[6]);
      float c20 =  X[1]*X[5]-X[2]*X[4];
      float c21 = -(X[0]*X[5]-X[2]*X[3]);
      float c22 =  X[0]*X[4]-X[1]*X[3];
      float det = X[0]*c00 + X[1]*c01 + X[2]*c02;
      float id = 0.5f / det;
      X[0]=0.5f*X[0]+c00*id; X[1]=0.5f*X[1]+c01*id; X[2]=0.5f*X[2]+c02*id;
      X[3]=0.5f*X[3]+c10*id; X[4]=0.5f*X[4]+c11*id; X[5]=0.5f*X[5]+c12_*id;
      X[6]=0.5f*X[6]+c20*id; X[7]=0.5f*X[7]+c21*id; X[8]=0.5f*X[8]+c22*id;
    }
    if (tid == 0) {
#pragma unroll
      for (int i = 0; i < 9; i++) sXf[i] = X[i];
#pragma unroll
      for (int k = 0; k < 3; k++)
        sXf[9+k] = cA[k] - (cB[0]*X[k] + cB[1]*X[3+k] + cB[2]*X[6+k]) + myY[k];
    }
  }
  __syncthreads();
  {
    float X0=sXf[0], X1=sXf[1], X2=sXf[2], X3=sXf[3], X4=sXf[4], X5=sXf[5],
          X6=sXf[6], X7=sXf[7], X8=sXf[8], t0=sXf[9], t1=sXf[10], t2=sXf[11];
    for (int p = 0; p < 4; p++) {
      int tok = p * 256 + tid;
      float x0 = x3buf[tok*3+0] - mx0;
      float x1 = x3buf[tok*3+1] - mx1;
      float x2 = x3buf[tok*3+2] - mx2;
      size_t t = (size_t)b * N_ + tok;
      out[t*3+0] = fmaf(x0, X0, fmaf(x1, X3, fmaf(x2, X6, t0)));
      out[t*3+1] = fmaf(x0, X1, fmaf(x1, X4, fmaf(x2, X7, t1)));
      out[t*3+2] = fmaf(x0, X2, fmaf(x1, X5, fmaf(x2, X8, t2)));
    }
  }
}

extern "C" void kernel_launch(void* const* d_in, const int* in_sizes, int n_in,
                              void* d_out, int out_size, void* d_ws, size_t ws_size,
                              hipStream_t stream) {
  const float* x_orig = (const float*)d_in[0];
  const float* y_orig = (const float*)d_in[1];
  const float* W_in   = (const float*)d_in[2];
  const float* b_in   = (const float*)d_in[3];
  const float* Wqkv_s = (const float*)d_in[4];
  const float* bqkv_s = (const float*)d_in[5];
  const float* Wo_s   = (const float*)d_in[6];
  const float* bo_s   = (const float*)d_in[7];
  const float* Wqkv_c = (const float*)d_in[8];
  const float* bqkv_c = (const float*)d_in[9];
  const float* Wo_c   = (const float*)d_in[10];
  const float* bo_c   = (const float*)d_in[11];
  const float* W_out  = (const float*)d_in[12];
  const float* b_out  = (const float*)d_in[13];
  float* ws = (float*)d_ws;

  k_all<<<32, 256, 0, stream>>>(x_orig, y_orig, W_in, b_in, Wqkv_s, bqkv_s,
                                Wo_s, bo_s, Wqkv_c, bqkv_c, Wo_c, bo_c,
                                W_out, b_out, ws, (float*)d_out);
}